// Round 1
// baseline (262.976 us; speedup 1.0000x reference)
//
#include <hip/hip_runtime.h>
#include <hip/hip_bf16.h>

#define GAT_ALPHA 0.2f

typedef short bf16x8 __attribute__((ext_vector_type(8)));
typedef float f32x4 __attribute__((ext_vector_type(4)));

__device__ __forceinline__ unsigned f2bf_u(float x) {
  union { float f; unsigned u; } v; v.f = x;
  return (v.u + 0x7fffu + ((v.u >> 16) & 1u)) >> 16;  // RNE to bf16
}
__device__ __forceinline__ unsigned short f2bf(float x) { return (unsigned short)f2bf_u(x); }

// HW packed f32->bf16 (RNE), 1 instr per pair vs ~7 for the emulation.
__device__ __forceinline__ unsigned pk_bf16(float lo, float hi) {
  unsigned r;
  asm("v_cvt_pk_bf16_f32 %0, %1, %2" : "=v"(r) : "v"(lo), "v"(hi));
  return r;
}

// DS-only barrier: drain LDS ops, leave global loads in flight across the
// barrier (plain __syncthreads() emits s_waitcnt vmcnt(0) which kills the
// cross-chunk load pipeline). "memory" clobber pins LDS/global ops on their
// side; compiler inserts counted vmcnt at actual register-consumption points.
#define DS_BARRIER() asm volatile("s_waitcnt lgkmcnt(0)\n\ts_barrier" ::: "memory")

// ---------------- kernel 0: W (512x256 f32) -> WT bf16 (256x512) ----------
__global__ void k_wt(const float* __restrict__ W, unsigned short* __restrict__ WT) {
  int kb = blockIdx.x * 8;       // 64 blocks
  int f = threadIdx.x;           // 256 threads = one f each
  uint4 o;
  o.x = pk_bf16(W[(kb + 0) * 256 + f], W[(kb + 1) * 256 + f]);
  o.y = pk_bf16(W[(kb + 2) * 256 + f], W[(kb + 3) * 256 + f]);
  o.z = pk_bf16(W[(kb + 4) * 256 + f], W[(kb + 5) * 256 + f]);
  o.w = pk_bf16(W[(kb + 6) * 256 + f], W[(kb + 7) * 256 + f]);
  *reinterpret_cast<uint4*>(WT + f * 512 + kb) = o;
}

// ---------------- kernel 1: WhT = (h@W)^T bf16 [b][f][n], + exp(f1/f2) ----
// Grid 512 (8 b x 64 node-groups of 32), 256 thr (4 waves).
// Barrier-free K-loop, register pipeline: WT depth-1, h depth-2.
__global__ __launch_bounds__(256, 2) void k_gemm1(
    const float* __restrict__ h, const unsigned short* __restrict__ WT,
    const float* __restrict__ avec,
    unsigned short* __restrict__ WhT,
    float* __restrict__ E1p, float* __restrict__ E1n,
    float* __restrict__ E2p, float* __restrict__ E2n)
{
  const int bx = blockIdx.x;
  const int b = bx & 7, ng = bx >> 3;
  const int n0 = ng * 32;
  const int t = threadIdx.x;
  const int lane = t & 63, w = t >> 6;
  const int l15 = lane & 15, q = lane >> 4;

  __shared__ __align__(16) unsigned short Wt[256 * 36];  // [f][36] pad
  __shared__ float f1a[32], f2a[32];
  if (t < 32) { f1a[t] = 0.f; f2a[t] = 0.f; }

  f32x4 acc[4][2];
#pragma unroll
  for (int i = 0; i < 4; ++i)
#pragma unroll
    for (int j = 0; j < 2; ++j) acc[i][j] = (f32x4){0.f, 0.f, 0.f, 0.f};

  const size_t hbase = ((size_t)(b * 2048 + n0)) * 512;
  const unsigned short* wtb = WT + (w * 64 + l15) * 512 + q * 8;
  const float* hrow0 = h + hbase + (size_t)l15 * 512 + q * 8;
  const float* hrow1 = h + hbase + (size_t)(16 + l15) * 512 + q * 8;

  // prologue: issue af(0), h(0), h(1)
  bf16x8 afA[4], afN[4];
  float4 hA[4], hB[4], hN[4];
#pragma unroll
  for (int mt = 0; mt < 4; ++mt) afA[mt] = *reinterpret_cast<const bf16x8*>(wtb + mt * 16 * 512);
  hA[0] = *reinterpret_cast<const float4*>(hrow0);
  hA[1] = *reinterpret_cast<const float4*>(hrow0 + 4);
  hA[2] = *reinterpret_cast<const float4*>(hrow1);
  hA[3] = *reinterpret_cast<const float4*>(hrow1 + 4);
  hB[0] = *reinterpret_cast<const float4*>(hrow0 + 32);
  hB[1] = *reinterpret_cast<const float4*>(hrow0 + 36);
  hB[2] = *reinterpret_cast<const float4*>(hrow1 + 32);
  hB[3] = *reinterpret_cast<const float4*>(hrow1 + 36);

#pragma unroll
  for (int k = 0; k < 16; ++k) {
    // issue af(k+1)
    if (k < 15) {
      const unsigned short* p = wtb + (k + 1) * 32;
#pragma unroll
      for (int mt = 0; mt < 4; ++mt) afN[mt] = *reinterpret_cast<const bf16x8*>(p + mt * 16 * 512);
    }
    // issue h(k+2)
    if (k < 14) {
      int o = (k + 2) * 32;
      hN[0] = *reinterpret_cast<const float4*>(hrow0 + o);
      hN[1] = *reinterpret_cast<const float4*>(hrow0 + o + 4);
      hN[2] = *reinterpret_cast<const float4*>(hrow1 + o);
      hN[3] = *reinterpret_cast<const float4*>(hrow1 + o + 4);
    }
    // convert h(k) -> bf16 fragments via HW cvt_pk, MFMA
    bf16x8 bfr[2];
#pragma unroll
    for (int nt = 0; nt < 2; ++nt) {
      float4 x0 = hA[nt * 2], x1 = hA[nt * 2 + 1];
      uint4 ub;
      ub.x = pk_bf16(x0.x, x0.y);
      ub.y = pk_bf16(x0.z, x0.w);
      ub.z = pk_bf16(x1.x, x1.y);
      ub.w = pk_bf16(x1.z, x1.w);
      bfr[nt] = *reinterpret_cast<bf16x8*>(&ub);
    }
#pragma unroll
    for (int mt = 0; mt < 4; ++mt)
#pragma unroll
      for (int nt = 0; nt < 2; ++nt)
        acc[mt][nt] = __builtin_amdgcn_mfma_f32_16x16x32_bf16(afA[mt], bfr[nt], acc[mt][nt], 0, 0, 0);
    // rotate stages (folded by unroll)
    if (k < 15) {
#pragma unroll
      for (int mt = 0; mt < 4; ++mt) afA[mt] = afN[mt];
#pragma unroll
      for (int i = 0; i < 4; ++i) hA[i] = hB[i];
#pragma unroll
      for (int i = 0; i < 4; ++i) hB[i] = hN[i];
    }
  }

  // stage into LDS [f][n] + f1/f2 partials
  float s1[2] = {0.f, 0.f}, s2[2] = {0.f, 0.f};
#pragma unroll
  for (int mt = 0; mt < 4; ++mt) {
#pragma unroll
    for (int nt = 0; nt < 2; ++nt) {
#pragma unroll
      for (int r = 0; r < 4; ++r) {
        int f = w * 64 + mt * 16 + q * 4 + r;
        float v = acc[mt][nt][r];
        Wt[f * 36 + nt * 16 + l15] = f2bf(v);
        s1[nt] += v * avec[f];
        s2[nt] += v * avec[256 + f];
      }
    }
  }
#pragma unroll
  for (int nt = 0; nt < 2; ++nt) {
    s1[nt] += __shfl_xor(s1[nt], 16); s1[nt] += __shfl_xor(s1[nt], 32);
    s2[nt] += __shfl_xor(s2[nt], 16); s2[nt] += __shfl_xor(s2[nt], 32);
  }
  __syncthreads();   // Wt visible, f1a/f2a init visible
  if (q == 0) {
#pragma unroll
    for (int nt = 0; nt < 2; ++nt) {
      atomicAdd(&f1a[nt * 16 + l15], s1[nt]);
      atomicAdd(&f2a[nt * 16 + l15], s2[nt]);
    }
  }
  // WhT stores: 8-byte lanes, 64-B segments per f-row
#pragma unroll
  for (int i = 0; i < 8; ++i) {
    int f = i * 32 + (t >> 3), g = t & 7;
    uint2 v = *reinterpret_cast<const uint2*>(Wt + f * 36 + g * 4);
    *reinterpret_cast<uint2*>(WhT + (size_t)(b * 256 + f) * 2048 + n0 + g * 4) = v;
  }
  __syncthreads();   // atomics complete
  if (t < 32) {
    int n = b * 2048 + n0 + t;
    float f1 = f1a[t], f2 = f2a[t];
    E1p[n] = __expf(f1);
    E1n[n] = __expf(GAT_ALPHA * f1);
    E2p[n] = __expf(f2);
    E2n[n] = __expf(GAT_ALPHA * f2);
  }
}

// build one A-fragment (8 cols of one row) and write it in fragment layout
__device__ __forceinline__ void build_frag(
    unsigned short* dst, int4 alo, int4 ahi, float e1p, float e1n,
    float4 epl, float4 eph, float4 enl, float4 enh, float& den)
{
  float p0 = alo.x ? fmaxf(e1p * epl.x, e1n * enl.x) : 0.f;
  float p1 = alo.y ? fmaxf(e1p * epl.y, e1n * enl.y) : 0.f;
  float p2 = alo.z ? fmaxf(e1p * epl.z, e1n * enl.z) : 0.f;
  float p3 = alo.w ? fmaxf(e1p * epl.w, e1n * enl.w) : 0.f;
  float p4 = ahi.x ? fmaxf(e1p * eph.x, e1n * enh.x) : 0.f;
  float p5 = ahi.y ? fmaxf(e1p * eph.y, e1n * enh.y) : 0.f;
  float p6 = ahi.z ? fmaxf(e1p * eph.z, e1n * enh.z) : 0.f;
  float p7 = ahi.w ? fmaxf(e1p * eph.w, e1n * enh.w) : 0.f;
  den += ((p0 + p1) + (p2 + p3)) + ((p4 + p5) + (p6 + p7));
  uint4 pk;
  pk.x = pk_bf16(p0, p1);
  pk.y = pk_bf16(p2, p3);
  pk.z = pk_bf16(p4, p5);
  pk.w = pk_bf16(p6, p7);
  *reinterpret_cast<uint4*>(dst) = pk;
}

// ---------------- kernel 2: out = elu(softmax-masked P @ Wh), fused -------
// Grid 256 (8 b x 32 row-groups of 64), 512 thr, 1 block/CU.
// Software pipeline: everything consumed in iter c was issued in iter c-1.
// Barriers are DS-only (lgkmcnt drain + s_barrier) so global prefetch loads
// stay in flight ACROSS barriers; compiler inserts counted vmcnt at use.
__global__ __launch_bounds__(512, 2) void k_gat(
    const int* __restrict__ adj, const unsigned short* __restrict__ WhT,
    const float* __restrict__ E1p, const float* __restrict__ E1n,
    const float* __restrict__ E2p, const float* __restrict__ E2n,
    float* __restrict__ out)
{
  const int bx = blockIdx.x;               // 256 blocks = 8 batches x 32 row-groups
  const int b = bx & 7, ig = bx >> 3;
  const int i0 = ig * 64;
  const int t = threadIdx.x;
  const int lane = t & 63, w = t >> 6;
  const int l15 = lane & 15, q = lane >> 4;
  const int m = t & 15, qk = (t >> 4) & 3, pp = t >> 6;
  const int rt0 = pp >> 2, ks = pp & 3;
  const int r0 = rt0 * 16 + m, r1 = r0 + 32;
  const int cb = ks * 32 + qk * 8;

  __shared__ __align__(16) unsigned short Pb[2][8192];  // 16 frags x 64 lanes x 16B
  __shared__ float den_l[64];
  if (t < 64) den_l[t] = 0.f;

  const float e1p0 = E1p[b * 2048 + i0 + r0], e1n0 = E1n[b * 2048 + i0 + r0];
  const float e1p1 = E1p[b * 2048 + i0 + r1], e1n1 = E1n[b * 2048 + i0 + r1];
  float d0 = 0.f, d1 = 0.f;

  f32x4 acc[4][2];
#pragma unroll
  for (int i = 0; i < 4; ++i)
#pragma unroll
    for (int j = 0; j < 2; ++j) acc[i][j] = (f32x4){0.f, 0.f, 0.f, 0.f};

  const size_t adj0 = ((size_t)(b * 2048 + i0 + r0)) * 2048 + cb;
  const size_t adj1 = adj0 + (size_t)32 * 2048;
  const int e2b = b * 2048 + cb;
  const unsigned short* Wb = WhT + (size_t)(b * 256 + w * 32) * 2048;

  // ---- prologue ----
  // chunk 0 raw
  int4 z0l = *reinterpret_cast<const int4*>(adj + adj0);
  int4 z0h = *reinterpret_cast<const int4*>(adj + adj0 + 4);
  int4 z1l = *reinterpret_cast<const int4*>(adj + adj1);
  int4 z1h = *reinterpret_cast<const int4*>(adj + adj1 + 4);
  float4 zpl = *reinterpret_cast<const float4*>(E2p + e2b);
  float4 zph = *reinterpret_cast<const float4*>(E2p + e2b + 4);
  float4 znl = *reinterpret_cast<const float4*>(E2n + e2b);
  float4 znh = *reinterpret_cast<const float4*>(E2n + e2b + 4);
  // B(0), adj(1), e2(1) in flight across the prologue barrier
  bf16x8 bcur[2][4], bnxt[2][4];
#pragma unroll
  for (int ct = 0; ct < 2; ++ct)
#pragma unroll
    for (int k2 = 0; k2 < 4; ++k2)
      bcur[ct][k2] = *reinterpret_cast<const bf16x8*>(
          Wb + (size_t)(ct * 16 + l15) * 2048 + k2 * 32 + q * 8);
  int4 A0l = *reinterpret_cast<const int4*>(adj + adj0 + 128);
  int4 A0h = *reinterpret_cast<const int4*>(adj + adj0 + 132);
  int4 A1l = *reinterpret_cast<const int4*>(adj + adj1 + 128);
  int4 A1h = *reinterpret_cast<const int4*>(adj + adj1 + 132);
  float4 Epl = *reinterpret_cast<const float4*>(E2p + e2b + 128);
  float4 Eph = *reinterpret_cast<const float4*>(E2p + e2b + 132);
  float4 Enl = *reinterpret_cast<const float4*>(E2n + e2b + 128);
  float4 Enh = *reinterpret_cast<const float4*>(E2n + e2b + 132);
  // construct chunk 0 (waits only on the chunk-0 loads; later loads are younger)
  build_frag(&Pb[0][(pp * 64 + lane) * 8], z0l, z0h, e1p0, e1n0, zpl, zph, znl, znh, d0);
  build_frag(&Pb[0][((pp + 8) * 64 + lane) * 8], z1l, z1h, e1p1, e1n1, zpl, zph, znl, znh, d1);
  DS_BARRIER();

#pragma unroll
  for (int c = 0; c < 16; ++c) {
    // 1. issue B(c+1)
    if (c < 15) {
      const unsigned short* p = Wb + (c + 1) * 128 + q * 8;
#pragma unroll
      for (int ct = 0; ct < 2; ++ct)
#pragma unroll
        for (int k2 = 0; k2 < 4; ++k2)
          bnxt[ct][k2] = *reinterpret_cast<const bf16x8*>(p + (size_t)(ct * 16 + l15) * 2048 + k2 * 32);
    }
    // 2. issue adj(c+2), e2(c+2)
    int4 nA0l, nA0h, nA1l, nA1h;
    float4 nEpl, nEph, nEnl, nEnh;
    if (c < 14) {
      int o = (c + 2) * 128;
      nA0l = *reinterpret_cast<const int4*>(adj + adj0 + o);
      nA0h = *reinterpret_cast<const int4*>(adj + adj0 + o + 4);
      nA1l = *reinterpret_cast<const int4*>(adj + adj1 + o);
      nA1h = *reinterpret_cast<const int4*>(adj + adj1 + o + 4);
      nEpl = *reinterpret_cast<const float4*>(E2p + e2b + o);
      nEph = *reinterpret_cast<const float4*>(E2p + e2b + o + 4);
      nEnl = *reinterpret_cast<const float4*>(E2n + e2b + o);
      nEnh = *reinterpret_cast<const float4*>(E2n + e2b + o + 4);
    }
    // 3. MFMA(c): A from LDS (arrived), B from registers (arrived) -> no waits
    const unsigned short* pb = &Pb[c & 1][0];
#pragma unroll
    for (int k2 = 0; k2 < 4; ++k2) {
      bf16x8 afr[4];
#pragma unroll
      for (int rt = 0; rt < 4; ++rt)
        afr[rt] = *reinterpret_cast<const bf16x8*>(pb + ((rt * 4 + k2) * 64 + lane) * 8);
#pragma unroll
      for (int rt = 0; rt < 4; ++rt)
#pragma unroll
        for (int ct = 0; ct < 2; ++ct)
          acc[rt][ct] = __builtin_amdgcn_mfma_f32_16x16x32_bf16(afr[rt], bcur[ct][k2], acc[rt][ct], 0, 0, 0);
    }
    // 4. construct(c+1) from registers (arrived) -> no waits
    if (c < 15) {
      unsigned short* wb = &Pb[(c + 1) & 1][0];
      build_frag(wb + (pp * 64 + lane) * 8, A0l, A0h, e1p0, e1n0, Epl, Eph, Enl, Enh, d0);
      build_frag(wb + ((pp + 8) * 64 + lane) * 8, A1l, A1h, e1p1, e1n1, Epl, Eph, Enl, Enh, d1);
    }
    // 5. DS-only barrier: orders Pb double-buffer; global prefetches issued
    //    at steps 1/2 remain in flight (no vmcnt(0) drain).
    if (c < 15) DS_BARRIER();
    // rotate stages (folded into SSA by full unroll)
    if (c < 15) {
#pragma unroll
      for (int ct = 0; ct < 2; ++ct)
#pragma unroll
        for (int k2 = 0; k2 < 4; ++k2) bcur[ct][k2] = bnxt[ct][k2];
    }
    if (c < 14) {
      A0l = nA0l; A0h = nA0h; A1l = nA1l; A1h = nA1h;
      Epl = nEpl; Eph = nEph; Enl = nEnl; Enh = nEnh;
    }
  }

  // denominator: reduce over qk lanes, then 4 row-tile waves combine via LDS
  d0 += __shfl_xor(d0, 16); d0 += __shfl_xor(d0, 32);
  d1 += __shfl_xor(d1, 16); d1 += __shfl_xor(d1, 32);
  if (lane < 16) {
    atomicAdd(&den_l[r0], d0);
    atomicAdd(&den_l[r1], d1);
  }
  __syncthreads();

  // epilogue: out = elu(acc/den); C row = rt*16+q*4+r, col f = w*32+ct*16+l15
#pragma unroll
  for (int rt = 0; rt < 4; ++rt) {
#pragma unroll
    for (int r = 0; r < 4; ++r) {
      int row = rt * 16 + q * 4 + r;
      float dinv = 1.0f / den_l[row];
      size_t ob = ((size_t)(b * 2048 + i0 + row)) * 256 + w * 32;
#pragma unroll
      for (int ct = 0; ct < 2; ++ct) {
        float v = acc[rt][ct][r] * dinv;
        v = v > 0.f ? v : (__expf(v) - 1.f);
        out[ob + ct * 16 + l15] = v;
      }
    }
  }
}

extern "C" void kernel_launch(void* const* d_in, const int* in_sizes, int n_in,
                              void* d_out, int out_size, void* d_ws, size_t ws_size,
                              hipStream_t stream) {
  const float* h   = (const float*)d_in[0];   // [8,2048,512] f32
  const int*   adj = (const int*)d_in[1];     // [8,2048,2048] i32
  const float* W   = (const float*)d_in[2];   // [512,256] f32
  const float* a   = (const float*)d_in[3];   // [512,1] f32
  float* out = (float*)d_out;                 // [8,2048,256] f32

  char* ws = (char*)d_ws;
  unsigned short* WhT = (unsigned short*)ws;                  // 8 MB   [8][256][2048] bf16
  unsigned short* WT  = (unsigned short*)(ws + 8388608);      // 256 KB [256][512] bf16
  float* E1p  = (float*)(ws + 8388608 + 262144);              // 64 KB each
  float* E1n  = E1p + 16384;
  float* E2p  = E1n + 16384;
  float* E2n  = E2p + 16384;

  k_wt<<<dim3(64), dim3(256), 0, stream>>>(W, WT);
  k_gemm1<<<dim3(512), dim3(256), 0, stream>>>(h, WT, a, WhT, E1p, E1n, E2p, E2n);
  k_gat<<<dim3(256), dim3(512), 0, stream>>>(adj, WhT, E1p, E1n, E2p, E2n, out);
}